// Round 3
// baseline (6986.452 us; speedup 1.0000x reference)
//
#include <hip/hip_runtime.h>

#define OUTC 64
#define BSH 7                     // 128 rows per bucket
#define BROWS (1 << BSH)
#define NB_MAX 1024               // supports N <= 131072
#define BIN_T 1024
#define CHUNK 12288               // elements per bin_pass chunk

// ---------------- bucket histogram (LDS-aggregated) ----------------
__global__ void hist_bucket(const int* __restrict__ rows, int nnz,
                            int* __restrict__ counts, int nb) {
    __shared__ int h[NB_MAX];
    for (int b = threadIdx.x; b < nb; b += blockDim.x) h[b] = 0;
    __syncthreads();
    int i  = blockIdx.x * blockDim.x + threadIdx.x;
    int st = gridDim.x * blockDim.x;
    for (; i < nnz; i += st) atomicAdd(&h[rows[i] >> BSH], 1);
    __syncthreads();
    for (int b = threadIdx.x; b < nb; b += blockDim.x)
        if (h[b]) atomicAdd(&counts[b], h[b]);
}

// ---------------- tiny scan over nb<=1024 bucket counts ----------------
__global__ void scan_small(const int* __restrict__ counts, int nb,
                           int* __restrict__ bptr, int* __restrict__ cursor) {
    __shared__ int s[1024];
    int t = threadIdx.x;
    int v = (t < nb) ? counts[t] : 0;
    s[t] = v;
    __syncthreads();
    for (int off = 1; off < 1024; off <<= 1) {
        int u = (t >= off) ? s[t - off] : 0;
        __syncthreads();
        s[t] += u;
        __syncthreads();
    }
    if (t < nb) {
        int ex = s[t] - v;      // exclusive
        bptr[t]   = ex;
        cursor[t] = ex;
    }
    if (t == 0) bptr[nb] = s[1023];   // grand total (zero-padded beyond nb)
}

// ---------------- LDS-staged binning: COO -> bucket-major packed int2 ----------------
// packed: x = col | (row_low7 << 24), y = float bits of val
__global__ __launch_bounds__(BIN_T) void bin_pass(
    const int* __restrict__ rows, const int* __restrict__ cols,
    const float* __restrict__ vals, int nnz,
    int* __restrict__ cursor, int2* __restrict__ outb, int nb) {
    __shared__ int2 staging[CHUNK];                 // 96 KB
    __shared__ unsigned short sbuck[CHUNK];         // 24 KB
    __shared__ int hist[NB_MAX];                    // counts, then per-chunk cursor
    __shared__ int lofs[NB_MAX];                    // exclusive local offsets
    __shared__ int gbase[NB_MAX];                   // global segment bases
    int t = threadIdx.x;
    for (long cb = (long)blockIdx.x * CHUNK; cb < nnz; cb += (long)gridDim.x * CHUNK) {
        int cn = (int)min((long)CHUNK, nnz - cb);
        for (int b = t; b < nb; b += BIN_T) hist[b] = 0;
        __syncthreads();
        for (int i = t; i < cn; i += BIN_T)
            atomicAdd(&hist[rows[cb + i] >> BSH], 1);
        __syncthreads();
        // exclusive scan of hist -> lofs (nb <= 1024 == BIN_T)
        int hv = (t < nb) ? hist[t] : 0;
        lofs[t] = hv;
        __syncthreads();
        for (int off = 1; off < 1024; off <<= 1) {
            int u = (t >= off) ? lofs[t - off] : 0;
            __syncthreads();
            lofs[t] += u;
            __syncthreads();
        }
        int ex = lofs[t] - hv;
        __syncthreads();
        lofs[t] = ex;
        if (t < nb && hv) gbase[t] = atomicAdd(&cursor[t], hv);
        __syncthreads();
        if (t < nb) hist[t] = ex;   // hist becomes local cursor
        __syncthreads();
        // place into staging, compact by bucket
        for (int i = t; i < cn; i += BIN_T) {
            int r = rows[cb + i];
            int b = r >> BSH;
            int p = atomicAdd(&hist[b], 1);
            staging[p] = make_int2(cols[cb + i] | ((r & (BROWS - 1)) << 24),
                                   __float_as_int(vals[cb + i]));
            sbuck[p] = (unsigned short)b;
        }
        __syncthreads();
        // coalesced copy-out: consecutive i within a bucket -> consecutive global
        for (int i = t; i < cn; i += BIN_T) {
            int b = sbuck[i];
            outb[gbase[b] + (i - lofs[b])] = staging[i];
        }
        __syncthreads();
    }
}

// ---------------- SpMM: block per bucket, LDS accumulator ----------------
template <bool RELU>
__global__ __launch_bounds__(256) void spmm_bucket(
    const int* __restrict__ bptr, const int2* __restrict__ binned,
    const float* __restrict__ B, const float* __restrict__ bias,
    float* __restrict__ out, int n, int nb) {
    __shared__ float acc[BROWS * OUTC];   // 32 KB
    int lane = threadIdx.x & 63;
    int wid  = threadIdx.x >> 6;          // 0..3
    for (int bkt = blockIdx.x; bkt < nb; bkt += gridDim.x) {
        for (int j = threadIdx.x; j < BROWS * OUTC; j += 256) acc[j] = 0.f;
        __syncthreads();
        int s = bptr[bkt], e = bptr[bkt + 1];
        int nfull = (e - s) & ~3;
        for (int i = s + (wid << 2); i < s + nfull; i += 16) {
            int2 p0 = binned[i], p1 = binned[i + 1], p2 = binned[i + 2], p3 = binned[i + 3];
            float b0 = B[(size_t)(p0.x & 0xFFFFFF) * OUTC + lane];
            float b1 = B[(size_t)(p1.x & 0xFFFFFF) * OUTC + lane];
            float b2 = B[(size_t)(p2.x & 0xFFFFFF) * OUTC + lane];
            float b3 = B[(size_t)(p3.x & 0xFFFFFF) * OUTC + lane];
            atomicAdd(&acc[((p0.x >> 24) & 127) * OUTC + lane], __int_as_float(p0.y) * b0);
            atomicAdd(&acc[((p1.x >> 24) & 127) * OUTC + lane], __int_as_float(p1.y) * b1);
            atomicAdd(&acc[((p2.x >> 24) & 127) * OUTC + lane], __int_as_float(p2.y) * b2);
            atomicAdd(&acc[((p3.x >> 24) & 127) * OUTC + lane], __int_as_float(p3.y) * b3);
        }
        if (wid == 0) {
            for (int i = s + nfull; i < e; ++i) {
                int2 p = binned[i];
                float b = B[(size_t)(p.x & 0xFFFFFF) * OUTC + lane];
                atomicAdd(&acc[((p.x >> 24) & 127) * OUTC + lane], __int_as_float(p.y) * b);
            }
        }
        __syncthreads();
        int row0 = bkt << BSH;
        int nr = min(BROWS, n - row0);
        float bi = RELU ? bias[lane] : 0.f;
        for (int r = wid; r < nr; r += 4) {
            float v = acc[r * OUTC + lane];
            if (RELU) v = fmaxf(v + bi, 0.f);
            out[(size_t)(row0 + r) * OUTC + lane] = v;
        }
        __syncthreads();
    }
}

// ---------------- fallback (atomic scatter, minimal ws) ----------------
__global__ void spmm_scatter(const int* __restrict__ rows, const int* __restrict__ cols,
                             const float* __restrict__ vals, const float* __restrict__ in,
                             float* __restrict__ out, int nnz) {
    int tid  = blockIdx.x * blockDim.x + threadIdx.x;
    int wave = tid >> 6, lane = threadIdx.x & 63;
    int nwav = (gridDim.x * blockDim.x) >> 6;
    for (int e = wave; e < nnz; e += nwav)
        atomicAdd(&out[(size_t)rows[e] * OUTC + lane],
                  vals[e] * in[(size_t)cols[e] * OUTC + lane]);
}
__global__ void bias_relu(float* __restrict__ p, const float* __restrict__ bias, long n4) {
    long i = (long)blockIdx.x * blockDim.x + threadIdx.x;
    long st = (long)gridDim.x * blockDim.x;
    for (; i < n4; i += st) {
        float4 v = reinterpret_cast<float4*>(p)[i];
        int cb = (int)((i & 15) << 2);
        v.x = fmaxf(v.x + bias[cb + 0], 0.f);
        v.y = fmaxf(v.y + bias[cb + 1], 0.f);
        v.z = fmaxf(v.z + bias[cb + 2], 0.f);
        v.w = fmaxf(v.w + bias[cb + 3], 0.f);
        reinterpret_cast<float4*>(p)[i] = v;
    }
}

static inline size_t align256(size_t x) { return (x + 255) & ~(size_t)255; }

extern "C" void kernel_launch(void* const* d_in, const int* in_sizes, int n_in,
                              void* d_out, int out_size, void* d_ws, size_t ws_size,
                              hipStream_t stream) {
    const int*   fidx = (const int*)d_in[0];
    const float* fval = (const float*)d_in[1];
    const int*   aidx = (const int*)d_in[2];
    const float* aval = (const float*)d_in[3];
    const float* W    = (const float*)d_in[4];
    const float* bias = (const float*)d_in[5];
    float* out = (float*)d_out;

    const int fnnz = in_sizes[1];
    const int annz = in_sizes[3];
    const int N    = out_size / OUTC;
    const int nb   = (N + BROWS - 1) >> BSH;

    const size_t NBY = (size_t)N * OUTC * sizeof(float);
    size_t off = 0;
    float* base   = (float*)((char*)d_ws + off); off += align256(NBY);
    float* tmp    = (float*)((char*)d_ws + off); off += align256(NBY);
    int2*  binned = (int2*)((char*)d_ws + off);
    off += align256((size_t)(fnnz > annz ? fnnz : annz) * sizeof(int2));
    int* counts = (int*)((char*)d_ws + off); off += align256((size_t)NB_MAX * 4);
    int* bptr   = (int*)((char*)d_ws + off); off += align256(((size_t)NB_MAX + 1) * 4);
    int* cursor = (int*)((char*)d_ws + off); off += align256((size_t)NB_MAX * 4);

    if (ws_size >= off && nb <= NB_MAX) {
        // ---- feature SpMM (fused bias+relu) ----
        hipMemsetAsync(counts, 0, (size_t)nb * 4, stream);
        hist_bucket<<<512, 256, 0, stream>>>(fidx, fnnz, counts, nb);
        scan_small<<<1, 1024, 0, stream>>>(counts, nb, bptr, cursor);
        bin_pass<<<256, BIN_T, 0, stream>>>(fidx, fidx + fnnz, fval, fnnz,
                                            cursor, binned, nb);
        spmm_bucket<true><<<nb, 256, 0, stream>>>(bptr, binned, W, bias, base, N, nb);
        // ---- adjacency: bin once, SpMM x3 ----
        hipMemsetAsync(counts, 0, (size_t)nb * 4, stream);
        hist_bucket<<<512, 256, 0, stream>>>(aidx, annz, counts, nb);
        scan_small<<<1, 1024, 0, stream>>>(counts, nb, bptr, cursor);
        bin_pass<<<256, BIN_T, 0, stream>>>(aidx, aidx + annz, aval, annz,
                                            cursor, binned, nb);
        spmm_bucket<false><<<nb, 256, 0, stream>>>(bptr, binned, base, nullptr, tmp, N, nb);
        spmm_bucket<false><<<nb, 256, 0, stream>>>(bptr, binned, tmp, nullptr, base, N, nb);
        spmm_bucket<false><<<nb, 256, 0, stream>>>(bptr, binned, base, nullptr, out, N, nb);
    } else {
        // ---- fallback: atomic scatter path ----
        hipMemsetAsync(base, 0, NBY, stream);
        spmm_scatter<<<4096, 256, 0, stream>>>(fidx, fidx + fnnz, fval, W, base, fnnz);
        bias_relu<<<2048, 256, 0, stream>>>(base, bias, (long)N * OUTC / 4);
        hipMemsetAsync(tmp, 0, NBY, stream);
        spmm_scatter<<<4096, 256, 0, stream>>>(aidx, aidx + annz, aval, base, tmp, annz);
        hipMemsetAsync(base, 0, NBY, stream);
        spmm_scatter<<<4096, 256, 0, stream>>>(aidx, aidx + annz, aval, tmp, base, annz);
        hipMemsetAsync(out, 0, NBY, stream);
        spmm_scatter<<<4096, 256, 0, stream>>>(aidx, aidx + annz, aval, base, out, annz);
    }
}

// Round 6
// 869.626 us; speedup vs baseline: 8.0339x; 8.0339x over previous
//
#include <hip/hip_runtime.h>

#define OUTC 64
#define BSH 7                     // 128 rows per bucket
#define BROWS (1 << BSH)
#define NB_MAX 1024               // supports N <= 131072
#define BIN_T 1024
#define CHUNK 12288               // elements per bin_pass chunk / sort staging cap
#define SORT_T 1024

// ---------------- bucket histogram (LDS-aggregated) ----------------
__global__ void hist_bucket(const int* __restrict__ rows, int nnz,
                            int* __restrict__ counts, int nb) {
    __shared__ int h[NB_MAX];
    for (int b = threadIdx.x; b < nb; b += blockDim.x) h[b] = 0;
    __syncthreads();
    int i  = blockIdx.x * blockDim.x + threadIdx.x;
    int st = gridDim.x * blockDim.x;
    for (; i < nnz; i += st) atomicAdd(&h[rows[i] >> BSH], 1);
    __syncthreads();
    for (int b = threadIdx.x; b < nb; b += blockDim.x)
        if (h[b]) atomicAdd(&counts[b], h[b]);
}

// ---------------- tiny scan over nb<=1024 bucket counts ----------------
__global__ void scan_small(const int* __restrict__ counts, int nb,
                           int* __restrict__ bptr, int* __restrict__ cursor) {
    __shared__ int s[1024];
    int t = threadIdx.x;
    int v = (t < nb) ? counts[t] : 0;
    s[t] = v;
    __syncthreads();
    for (int off = 1; off < 1024; off <<= 1) {
        int u = (t >= off) ? s[t - off] : 0;
        __syncthreads();
        s[t] += u;
        __syncthreads();
    }
    if (t < nb) {
        int ex = s[t] - v;
        bptr[t]   = ex;
        cursor[t] = ex;
    }
    if (t == 0) bptr[nb] = s[1023];
}

// ---------------- LDS-staged binning: COO -> bucket-major packed int2 ----------------
// packed: x = col | (row_low7 << 24), y = float bits of val
__global__ __launch_bounds__(BIN_T) void bin_pass(
    const int* __restrict__ rows, const int* __restrict__ cols,
    const float* __restrict__ vals, int nnz,
    int* __restrict__ cursor, int2* __restrict__ outb, int nb) {
    __shared__ int2 staging[CHUNK];                 // 96 KB
    __shared__ unsigned short sbuck[CHUNK];         // 24 KB
    __shared__ int hist[NB_MAX];
    __shared__ int lofs[NB_MAX];
    __shared__ int gbase[NB_MAX];
    int t = threadIdx.x;
    for (long cb = (long)blockIdx.x * CHUNK; cb < nnz; cb += (long)gridDim.x * CHUNK) {
        int cn = (int)min((long)CHUNK, nnz - cb);
        for (int b = t; b < nb; b += BIN_T) hist[b] = 0;
        __syncthreads();
        for (int i = t; i < cn; i += BIN_T)
            atomicAdd(&hist[rows[cb + i] >> BSH], 1);
        __syncthreads();
        int hv = (t < nb) ? hist[t] : 0;
        lofs[t] = hv;
        __syncthreads();
        for (int off = 1; off < 1024; off <<= 1) {
            int u = (t >= off) ? lofs[t - off] : 0;
            __syncthreads();
            lofs[t] += u;
            __syncthreads();
        }
        int ex = lofs[t] - hv;
        __syncthreads();
        lofs[t] = ex;
        if (t < nb && hv) gbase[t] = atomicAdd(&cursor[t], hv);
        __syncthreads();
        if (t < nb) hist[t] = ex;   // hist becomes local placement cursor
        __syncthreads();
        for (int i = t; i < cn; i += BIN_T) {
            int r = rows[cb + i];
            int b = r >> BSH;
            int p = atomicAdd(&hist[b], 1);
            staging[p] = make_int2(cols[cb + i] | ((r & (BROWS - 1)) << 24),
                                   __float_as_int(vals[cb + i]));
            sbuck[p] = (unsigned short)b;
        }
        __syncthreads();
        for (int i = t; i < cn; i += BIN_T) {
            int b = sbuck[i];
            outb[gbase[b] + (i - lofs[b])] = staging[i];
        }
        __syncthreads();
    }
}

// ---------------- within-bucket counting sort -> exact row-sorted CSR ----------------
// in: bucket-major packed (col | row7<<24, val); out: row-sorted (col, val) + rowptr
__global__ __launch_bounds__(SORT_T) void sort_bucket(
    const int* __restrict__ bptr, const int2* __restrict__ in,
    int2* __restrict__ out, int* __restrict__ rowptr, int n, int nb) {
    __shared__ int2 staging[CHUNK];     // 96 KB
    __shared__ int rowcnt[BROWS];
    __shared__ int sc[BROWS];
    __shared__ int rowofs[BROWS];
    __shared__ int rcur[BROWS];
    int t = threadIdx.x;
    for (int bkt = blockIdx.x; bkt < nb; bkt += gridDim.x) {
        int s = bptr[bkt], e = bptr[bkt + 1];
        int cnt = e - s;
        if (t < BROWS) rowcnt[t] = 0;
        __syncthreads();
        for (int i = t; i < cnt; i += SORT_T)
            atomicAdd(&rowcnt[(in[s + i].x >> 24) & (BROWS - 1)], 1);
        __syncthreads();
        // exclusive scan of 128 counters (all threads hit barriers)
        int v = (t < BROWS) ? rowcnt[t] : 0;
        if (t < BROWS) sc[t] = v;
        __syncthreads();
        for (int off = 1; off < BROWS; off <<= 1) {
            int u = 0;
            if (t < BROWS && t >= off) u = sc[t - off];
            __syncthreads();
            if (t < BROWS) sc[t] += u;
            __syncthreads();
        }
        if (t < BROWS) {
            int ex = sc[t] - v;
            rowofs[t] = ex;
            rcur[t]   = ex;
            int row0 = bkt << BSH;
            if (row0 + t < n) rowptr[row0 + t] = s + ex;
        }
        if (t == 0 && bkt == nb - 1) rowptr[n] = e;
        __syncthreads();
        if (cnt <= CHUNK) {
            for (int i = t; i < cnt; i += SORT_T) {
                int2 x = in[s + i];
                int r  = (x.x >> 24) & (BROWS - 1);
                int p  = atomicAdd(&rcur[r], 1);
                staging[p] = make_int2(x.x & 0xFFFFFF, x.y);
            }
            __syncthreads();
            for (int i = t; i < cnt; i += SORT_T) out[s + i] = staging[i];
        } else {
            // impossible-for-this-data fallback: direct (still correct)
            for (int i = t; i < cnt; i += SORT_T) {
                int2 x = in[s + i];
                int r  = (x.x >> 24) & (BROWS - 1);
                int p  = atomicAdd(&rcur[r], 1);
                out[s + p] = make_int2(x.x & 0xFFFFFF, x.y);
            }
        }
        __syncthreads();
    }
}

// ---------------- gather SpMM: one wave per row, lane = channel ----------------
template <bool RELU>
__global__ void spmm_gather(const int* __restrict__ rowptr, const int2* __restrict__ csr,
                            const float* __restrict__ B, const float* __restrict__ bias,
                            float* __restrict__ out, int nrows) {
    int wave = (blockIdx.x * blockDim.x + threadIdx.x) >> 6;
    int lane = threadIdx.x & 63;
    if (wave >= nrows) return;
    int s = rowptr[wave], e = rowptr[wave + 1];
    float acc = 0.f;
    int i = s;
    for (; i + 4 <= e; i += 4) {
        int2 p0 = csr[i];
        int2 p1 = csr[i + 1];
        int2 p2 = csr[i + 2];
        int2 p3 = csr[i + 3];
        float b0 = B[(size_t)p0.x * OUTC + lane];
        float b1 = B[(size_t)p1.x * OUTC + lane];
        float b2 = B[(size_t)p2.x * OUTC + lane];
        float b3 = B[(size_t)p3.x * OUTC + lane];
        acc += __int_as_float(p0.y) * b0;
        acc += __int_as_float(p1.y) * b1;
        acc += __int_as_float(p2.y) * b2;
        acc += __int_as_float(p3.y) * b3;
    }
    for (; i < e; ++i) {
        int2 p = csr[i];
        acc += __int_as_float(p.y) * B[(size_t)p.x * OUTC + lane];
    }
    if (RELU) acc = fmaxf(acc + bias[lane], 0.f);
    out[(size_t)wave * OUTC + lane] = acc;
}

// ---------------- fallback (atomic scatter, minimal ws) ----------------
__global__ void spmm_scatter(const int* __restrict__ rows, const int* __restrict__ cols,
                             const float* __restrict__ vals, const float* __restrict__ in,
                             float* __restrict__ out, int nnz) {
    int tid  = blockIdx.x * blockDim.x + threadIdx.x;
    int wave = tid >> 6, lane = threadIdx.x & 63;
    int nwav = (gridDim.x * blockDim.x) >> 6;
    for (int e = wave; e < nnz; e += nwav)
        atomicAdd(&out[(size_t)rows[e] * OUTC + lane],
                  vals[e] * in[(size_t)cols[e] * OUTC + lane]);
}
__global__ void bias_relu(float* __restrict__ p, const float* __restrict__ bias, long n4) {
    long i = (long)blockIdx.x * blockDim.x + threadIdx.x;
    long st = (long)gridDim.x * blockDim.x;
    for (; i < n4; i += st) {
        float4 v = reinterpret_cast<float4*>(p)[i];
        int cb = (int)((i & 15) << 2);
        v.x = fmaxf(v.x + bias[cb + 0], 0.f);
        v.y = fmaxf(v.y + bias[cb + 1], 0.f);
        v.z = fmaxf(v.z + bias[cb + 2], 0.f);
        v.w = fmaxf(v.w + bias[cb + 3], 0.f);
        reinterpret_cast<float4*>(p)[i] = v;
    }
}

static inline size_t align256(size_t x) { return (x + 255) & ~(size_t)255; }

extern "C" void kernel_launch(void* const* d_in, const int* in_sizes, int n_in,
                              void* d_out, int out_size, void* d_ws, size_t ws_size,
                              hipStream_t stream) {
    const int*   fidx = (const int*)d_in[0];
    const float* fval = (const float*)d_in[1];
    const int*   aidx = (const int*)d_in[2];
    const float* aval = (const float*)d_in[3];
    const float* W    = (const float*)d_in[4];
    const float* bias = (const float*)d_in[5];
    float* out = (float*)d_out;

    const int fnnz = in_sizes[1];
    const int annz = in_sizes[3];
    const int N    = out_size / OUTC;
    const int nb   = (N + BROWS - 1) >> BSH;

    // Arena layout, time-multiplexed (S = one dense [N,64] fp32 buffer):
    //  [0,2S)  feat binned      -> later base [0,S) + adj binned [S,2S)
    //  [2S,4S) feat csr         -> later adj csr [2S,3S) + tmp [3S,4S)
    const size_t S = align256((size_t)N * OUTC * sizeof(float));
    char* w = (char*)d_ws;
    int2*  featBinned = (int2*)(w);
    int2*  featCsr    = (int2*)(w + 2 * S);
    float* base       = (float*)(w);
    int2*  adjBinned  = (int2*)(w + S);
    int2*  adjCsr     = (int2*)(w + 2 * S);
    float* tmp        = (float*)(w + 3 * S);
    size_t off = 4 * S;
    int* counts = (int*)(w + off); off += align256((size_t)NB_MAX * 4);
    int* bptr   = (int*)(w + off); off += align256(((size_t)NB_MAX + 1) * 4);
    int* cursor = (int*)(w + off); off += align256((size_t)NB_MAX * 4);
    int* rowptr = (int*)(w + off); off += align256(((size_t)N + 1) * 4);

    const int gatherBlocks = (N * 64 + 255) / 256;

    if (ws_size >= off && nb <= NB_MAX &&
        (size_t)fnnz * sizeof(int2) <= 2 * S && (size_t)annz * sizeof(int2) <= S) {
        // ---- feature CSR build ----
        hipMemsetAsync(counts, 0, (size_t)nb * 4, stream);
        hist_bucket<<<512, 256, 0, stream>>>(fidx, fnnz, counts, nb);
        scan_small<<<1, 1024, 0, stream>>>(counts, nb, bptr, cursor);
        bin_pass<<<256, BIN_T, 0, stream>>>(fidx, fidx + fnnz, fval, fnnz,
                                            cursor, featBinned, nb);
        sort_bucket<<<nb, SORT_T, 0, stream>>>(bptr, featBinned, featCsr, rowptr, N, nb);
        // ---- feature SpMM (fused bias+relu), writes base (frees featBinned) ----
        spmm_gather<true><<<gatherBlocks, 256, 0, stream>>>(rowptr, featCsr, W, bias,
                                                            base, N);
        // ---- adjacency CSR build (featCsr now dead) ----
        hipMemsetAsync(counts, 0, (size_t)nb * 4, stream);
        hist_bucket<<<512, 256, 0, stream>>>(aidx, annz, counts, nb);
        scan_small<<<1, 1024, 0, stream>>>(counts, nb, bptr, cursor);
        bin_pass<<<256, BIN_T, 0, stream>>>(aidx, aidx + annz, aval, annz,
                                            cursor, adjBinned, nb);
        sort_bucket<<<nb, SORT_T, 0, stream>>>(bptr, adjBinned, adjCsr, rowptr, N, nb);
        // ---- 3 adjacency SpMMs ----
        spmm_gather<false><<<gatherBlocks, 256, 0, stream>>>(rowptr, adjCsr, base,
                                                             nullptr, tmp, N);
        spmm_gather<false><<<gatherBlocks, 256, 0, stream>>>(rowptr, adjCsr, tmp,
                                                             nullptr, base, N);
        spmm_gather<false><<<gatherBlocks, 256, 0, stream>>>(rowptr, adjCsr, base,
                                                             nullptr, out, N);
    } else {
        // ---- fallback: atomic scatter path (needs 2S) ----
        float* fb0 = (float*)w;
        float* fb1 = (float*)(w + S);
        const size_t NBY = (size_t)N * OUTC * sizeof(float);
        hipMemsetAsync(fb0, 0, NBY, stream);
        spmm_scatter<<<4096, 256, 0, stream>>>(fidx, fidx + fnnz, fval, W, fb0, fnnz);
        bias_relu<<<2048, 256, 0, stream>>>(fb0, bias, (long)N * OUTC / 4);
        hipMemsetAsync(fb1, 0, NBY, stream);
        spmm_scatter<<<4096, 256, 0, stream>>>(aidx, aidx + annz, aval, fb0, fb1, annz);
        hipMemsetAsync(fb0, 0, NBY, stream);
        spmm_scatter<<<4096, 256, 0, stream>>>(aidx, aidx + annz, aval, fb1, fb0, annz);
        hipMemsetAsync(out, 0, NBY, stream);
        spmm_scatter<<<4096, 256, 0, stream>>>(aidx, aidx + annz, aval, fb0, out, annz);
    }
}

// Round 8
// 765.500 us; speedup vs baseline: 9.1267x; 1.1360x over previous
//
#include <hip/hip_runtime.h>

#define OUTC 64
#define BSH 7                     // 128 rows per bucket
#define BROWS (1 << BSH)
#define NB_MAX 1024               // supports N <= 131072
#define BIN_T 1024
#define CHUNK 12288               // elements per bin_pass chunk / sort staging cap
#define SORT_T 1024

// ---------------- bucket histogram (LDS-aggregated) ----------------
__global__ void hist_bucket(const int* __restrict__ rows, int nnz,
                            int* __restrict__ counts, int nb) {
    __shared__ int h[NB_MAX];
    for (int b = threadIdx.x; b < nb; b += blockDim.x) h[b] = 0;
    __syncthreads();
    int i  = blockIdx.x * blockDim.x + threadIdx.x;
    int st = gridDim.x * blockDim.x;
    for (; i < nnz; i += st) atomicAdd(&h[rows[i] >> BSH], 1);
    __syncthreads();
    for (int b = threadIdx.x; b < nb; b += blockDim.x)
        if (h[b]) atomicAdd(&counts[b], h[b]);
}

// ---------------- tiny scan over nb<=1024 bucket counts ----------------
__global__ void scan_small(const int* __restrict__ counts, int nb,
                           int* __restrict__ bptr, int* __restrict__ cursor) {
    __shared__ int s[1024];
    int t = threadIdx.x;
    int v = (t < nb) ? counts[t] : 0;
    s[t] = v;
    __syncthreads();
    for (int off = 1; off < 1024; off <<= 1) {
        int u = (t >= off) ? s[t - off] : 0;
        __syncthreads();
        s[t] += u;
        __syncthreads();
    }
    if (t < nb) {
        int ex = s[t] - v;
        bptr[t]   = ex;
        cursor[t] = ex;
    }
    if (t == 0) bptr[nb] = s[1023];
}

// ---------------- LDS-staged binning: COO -> bucket-major packed int2 ----------------
// packed: x = col | (row_low7 << 24), y = float bits of val
__global__ __launch_bounds__(BIN_T) void bin_pass(
    const int* __restrict__ rows, const int* __restrict__ cols,
    const float* __restrict__ vals, int nnz,
    int* __restrict__ cursor, int2* __restrict__ outb, int nb) {
    __shared__ int2 staging[CHUNK];                 // 96 KB
    __shared__ unsigned short sbuck[CHUNK];         // 24 KB
    __shared__ int hist[NB_MAX];
    __shared__ int lofs[NB_MAX];
    __shared__ int gbase[NB_MAX];
    int t = threadIdx.x;
    for (long cb = (long)blockIdx.x * CHUNK; cb < nnz; cb += (long)gridDim.x * CHUNK) {
        int cn = (int)min((long)CHUNK, nnz - cb);
        for (int b = t; b < nb; b += BIN_T) hist[b] = 0;
        __syncthreads();
        for (int i = t; i < cn; i += BIN_T)
            atomicAdd(&hist[rows[cb + i] >> BSH], 1);
        __syncthreads();
        int hv = (t < nb) ? hist[t] : 0;
        lofs[t] = hv;
        __syncthreads();
        for (int off = 1; off < 1024; off <<= 1) {
            int u = (t >= off) ? lofs[t - off] : 0;
            __syncthreads();
            lofs[t] += u;
            __syncthreads();
        }
        int ex = lofs[t] - hv;
        __syncthreads();
        lofs[t] = ex;
        if (t < nb && hv) gbase[t] = atomicAdd(&cursor[t], hv);
        __syncthreads();
        if (t < nb) hist[t] = ex;   // hist becomes local placement cursor
        __syncthreads();
        for (int i = t; i < cn; i += BIN_T) {
            int r = rows[cb + i];
            int b = r >> BSH;
            int p = atomicAdd(&hist[b], 1);
            staging[p] = make_int2(cols[cb + i] | ((r & (BROWS - 1)) << 24),
                                   __float_as_int(vals[cb + i]));
            sbuck[p] = (unsigned short)b;
        }
        __syncthreads();
        for (int i = t; i < cn; i += BIN_T) {
            int b = sbuck[i];
            outb[gbase[b] + (i - lofs[b])] = staging[i];
        }
        __syncthreads();
    }
}

// ---------------- within-bucket counting sort -> exact row-sorted CSR ----------------
// in: bucket-major packed (col | row7<<24, val); out: row-sorted (col, val) + rowptr
__global__ __launch_bounds__(SORT_T) void sort_bucket(
    const int* __restrict__ bptr, const int2* __restrict__ in,
    int2* __restrict__ out, int* __restrict__ rowptr, int n, int nb) {
    __shared__ int2 staging[CHUNK];     // 96 KB
    __shared__ int rowcnt[BROWS];
    __shared__ int sc[BROWS];
    __shared__ int rowofs[BROWS];
    __shared__ int rcur[BROWS];
    int t = threadIdx.x;
    for (int bkt = blockIdx.x; bkt < nb; bkt += gridDim.x) {
        int s = bptr[bkt], e = bptr[bkt + 1];
        int cnt = e - s;
        if (t < BROWS) rowcnt[t] = 0;
        __syncthreads();
        for (int i = t; i < cnt; i += SORT_T)
            atomicAdd(&rowcnt[(in[s + i].x >> 24) & (BROWS - 1)], 1);
        __syncthreads();
        // exclusive scan of 128 counters (all threads hit barriers)
        int v = (t < BROWS) ? rowcnt[t] : 0;
        if (t < BROWS) sc[t] = v;
        __syncthreads();
        for (int off = 1; off < BROWS; off <<= 1) {
            int u = 0;
            if (t < BROWS && t >= off) u = sc[t - off];
            __syncthreads();
            if (t < BROWS) sc[t] += u;
            __syncthreads();
        }
        if (t < BROWS) {
            int ex = sc[t] - v;
            rowofs[t] = ex;
            rcur[t]   = ex;
            int row0 = bkt << BSH;
            if (row0 + t < n) rowptr[row0 + t] = s + ex;
        }
        if (t == 0 && bkt == nb - 1) rowptr[n] = e;
        __syncthreads();
        if (cnt <= CHUNK) {
            for (int i = t; i < cnt; i += SORT_T) {
                int2 x = in[s + i];
                int r  = (x.x >> 24) & (BROWS - 1);
                int p  = atomicAdd(&rcur[r], 1);
                staging[p] = make_int2(x.x & 0xFFFFFF, x.y);
            }
            __syncthreads();
            for (int i = t; i < cnt; i += SORT_T) out[s + i] = staging[i];
        } else {
            // impossible-for-this-data fallback: direct (still correct)
            for (int i = t; i < cnt; i += SORT_T) {
                int2 x = in[s + i];
                int r  = (x.x >> 24) & (BROWS - 1);
                int p  = atomicAdd(&rcur[r], 1);
                out[s + p] = make_int2(x.x & 0xFFFFFF, x.y);
            }
        }
        __syncthreads();
    }
}

// ---------------- gather SpMM: one wave per row, lane = channel ----------------
// readfirstlane-hoisted: row index in SGPR -> metadata via scalar loads (s_load),
// per-nnz VALU reduced to the gather address add + fma.
template <bool RELU>
__global__ __launch_bounds__(256) void spmm_gather(
    const int* __restrict__ rowptr, const int2* __restrict__ csr,
    const float* __restrict__ B, const float* __restrict__ bias,
    float* __restrict__ out, int nrows) {
    int wave = __builtin_amdgcn_readfirstlane(
        (int)((blockIdx.x * blockDim.x + threadIdx.x) >> 6));
    int lane = threadIdx.x & 63;
    if (wave >= nrows) return;
    int s = rowptr[wave], e = rowptr[wave + 1];
    const float* Bl = B + lane;          // per-lane base; col offset is scalar
    float acc = 0.f;
    int i = s;
    for (; i + 4 <= e; i += 4) {
        int2 p0 = csr[i];
        int2 p1 = csr[i + 1];
        int2 p2 = csr[i + 2];
        int2 p3 = csr[i + 3];
        float b0 = Bl[(size_t)p0.x * OUTC];
        float b1 = Bl[(size_t)p1.x * OUTC];
        float b2 = Bl[(size_t)p2.x * OUTC];
        float b3 = Bl[(size_t)p3.x * OUTC];
        acc += __int_as_float(p0.y) * b0;
        acc += __int_as_float(p1.y) * b1;
        acc += __int_as_float(p2.y) * b2;
        acc += __int_as_float(p3.y) * b3;
    }
    for (; i < e; ++i) {
        int2 p = csr[i];
        acc += __int_as_float(p.y) * Bl[(size_t)p.x * OUTC];
    }
    if (RELU) acc = fmaxf(acc + bias[lane], 0.f);
    out[(size_t)wave * OUTC + lane] = acc;
}

// ---------------- fallback (atomic scatter, minimal ws) ----------------
__global__ void spmm_scatter(const int* __restrict__ rows, const int* __restrict__ cols,
                             const float* __restrict__ vals, const float* __restrict__ in,
                             float* __restrict__ out, int nnz) {
    int tid  = blockIdx.x * blockDim.x + threadIdx.x;
    int wave = tid >> 6, lane = threadIdx.x & 63;
    int nwav = (gridDim.x * blockDim.x) >> 6;
    for (int e = wave; e < nnz; e += nwav)
        atomicAdd(&out[(size_t)rows[e] * OUTC + lane],
                  vals[e] * in[(size_t)cols[e] * OUTC + lane]);
}
__global__ void bias_relu(float* __restrict__ p, const float* __restrict__ bias, long n4) {
    long i = (long)blockIdx.x * blockDim.x + threadIdx.x;
    long st = (long)gridDim.x * blockDim.x;
    for (; i < n4; i += st) {
        float4 v = reinterpret_cast<float4*>(p)[i];
        int cb = (int)((i & 15) << 2);
        v.x = fmaxf(v.x + bias[cb + 0], 0.f);
        v.y = fmaxf(v.y + bias[cb + 1], 0.f);
        v.z = fmaxf(v.z + bias[cb + 2], 0.f);
        v.w = fmaxf(v.w + bias[cb + 3], 0.f);
        reinterpret_cast<float4*>(p)[i] = v;
    }
}

static inline size_t align256(size_t x) { return (x + 255) & ~(size_t)255; }

extern "C" void kernel_launch(void* const* d_in, const int* in_sizes, int n_in,
                              void* d_out, int out_size, void* d_ws, size_t ws_size,
                              hipStream_t stream) {
    const int*   fidx = (const int*)d_in[0];
    const float* fval = (const float*)d_in[1];
    const int*   aidx = (const int*)d_in[2];
    const float* aval = (const float*)d_in[3];
    const float* W    = (const float*)d_in[4];
    const float* bias = (const float*)d_in[5];
    float* out = (float*)d_out;

    const int fnnz = in_sizes[1];
    const int annz = in_sizes[3];
    const int N    = out_size / OUTC;
    const int nb   = (N + BROWS - 1) >> BSH;

    // Arena layout, time-multiplexed (S = one dense [N,64] fp32 buffer):
    //  [0,2S)  feat binned      -> later base [0,S) + adj binned [S,2S)
    //  [2S,4S) feat csr         -> later adj csr [2S,3S) + tmp [3S,4S)
    const size_t S = align256((size_t)N * OUTC * sizeof(float));
    char* w = (char*)d_ws;
    int2*  featBinned = (int2*)(w);
    int2*  featCsr    = (int2*)(w + 2 * S);
    float* base       = (float*)(w);
    int2*  adjBinned  = (int2*)(w + S);
    int2*  adjCsr     = (int2*)(w + 2 * S);
    float* tmp        = (float*)(w + 3 * S);
    size_t off = 4 * S;
    int* counts = (int*)(w + off); off += align256((size_t)NB_MAX * 4);
    int* bptr   = (int*)(w + off); off += align256(((size_t)NB_MAX + 1) * 4);
    int* cursor = (int*)(w + off); off += align256((size_t)NB_MAX * 4);
    int* rowptr = (int*)(w + off); off += align256(((size_t)N + 1) * 4);

    const int gatherBlocks = (N * 64 + 255) / 256;

    if (ws_size >= off && nb <= NB_MAX &&
        (size_t)fnnz * sizeof(int2) <= 2 * S && (size_t)annz * sizeof(int2) <= S) {
        // ---- feature CSR build ----
        hipMemsetAsync(counts, 0, (size_t)nb * 4, stream);
        hist_bucket<<<512, 256, 0, stream>>>(fidx, fnnz, counts, nb);
        scan_small<<<1, 1024, 0, stream>>>(counts, nb, bptr, cursor);
        bin_pass<<<256, BIN_T, 0, stream>>>(fidx, fidx + fnnz, fval, fnnz,
                                            cursor, featBinned, nb);
        sort_bucket<<<nb, SORT_T, 0, stream>>>(bptr, featBinned, featCsr, rowptr, N, nb);
        // ---- feature SpMM (fused bias+relu), writes base (frees featBinned) ----
        spmm_gather<true><<<gatherBlocks, 256, 0, stream>>>(rowptr, featCsr, W, bias,
                                                            base, N);
        // ---- adjacency CSR build (featCsr now dead) ----
        hipMemsetAsync(counts, 0, (size_t)nb * 4, stream);
        hist_bucket<<<512, 256, 0, stream>>>(aidx, annz, counts, nb);
        scan_small<<<1, 1024, 0, stream>>>(counts, nb, bptr, cursor);
        bin_pass<<<256, BIN_T, 0, stream>>>(aidx, aidx + annz, aval, annz,
                                            cursor, adjBinned, nb);
        sort_bucket<<<nb, SORT_T, 0, stream>>>(bptr, adjBinned, adjCsr, rowptr, N, nb);
        // ---- 3 adjacency SpMMs ----
        spmm_gather<false><<<gatherBlocks, 256, 0, stream>>>(rowptr, adjCsr, base,
                                                             nullptr, tmp, N);
        spmm_gather<false><<<gatherBlocks, 256, 0, stream>>>(rowptr, adjCsr, tmp,
                                                             nullptr, base, N);
        spmm_gather<false><<<gatherBlocks, 256, 0, stream>>>(rowptr, adjCsr, base,
                                                             nullptr, out, N);
    } else {
        // ---- fallback: atomic scatter path (needs 2S) ----
        float* fb0 = (float*)w;
        float* fb1 = (float*)(w + S);
        const size_t NBY = (size_t)N * OUTC * sizeof(float);
        hipMemsetAsync(fb0, 0, NBY, stream);
        spmm_scatter<<<4096, 256, 0, stream>>>(fidx, fidx + fnnz, fval, W, fb0, fnnz);
        bias_relu<<<2048, 256, 0, stream>>>(fb0, bias, (long)N * OUTC / 4);
        hipMemsetAsync(fb1, 0, NBY, stream);
        spmm_scatter<<<4096, 256, 0, stream>>>(aidx, aidx + annz, aval, fb0, fb1, annz);
        hipMemsetAsync(fb0, 0, NBY, stream);
        spmm_scatter<<<4096, 256, 0, stream>>>(aidx, aidx + annz, aval, fb1, fb0, annz);
        hipMemsetAsync(out, 0, NBY, stream);
        spmm_scatter<<<4096, 256, 0, stream>>>(aidx, aidx + annz, aval, fb0, out, annz);
    }
}